// Round 1
// baseline (2396.399 us; speedup 1.0000x reference)
//
#include <hip/hip_runtime.h>
#include <cmath>

#define HH 256
#define WW 256
#define TTT 48
#define PLANE (HH * WW * TTT)

#if defined(__has_builtin)
#if __has_builtin(__builtin_amdgcn_exp2f)
#define EXP2F(x) __builtin_amdgcn_exp2f(x)
#else
#define EXP2F(x) exp2f(x)
#endif
#else
#define EXP2F(x) exp2f(x)
#endif

union F4 { float4 v; float f[4]; };

// One thread owns 4 consecutive t-centers of one (y,x) column.
// Block: 192 threads = 12 t-chunks x 16 x-columns, one y row. Grid: (W/16, H).
__global__ __launch_bounds__(192, 2)
void stat_denoise(const float* __restrict__ images,
                  const float* __restrict__ guidance,
                  const float* __restrict__ estimands,
                  const float* __restrict__ variance,
                  const float* __restrict__ sigma_inv,
                  const int* __restrict__ spp_ptr,
                  float* __restrict__ out)
{
    const int tid = threadIdx.x;
    const int tg  = tid % 12;           // t-chunk index, t0 = 4*tg
    const int xl  = tid / 12;           // 0..15
    const int x   = (int)blockIdx.x * 16 + xl;
    const int y   = (int)blockIdx.y;
    const int t0  = tg * 4;

    const float sppf  = (float)(*spp_ptr);
    const float T2f   = 2.8070337683438042f * 2.8070337683438042f;
    const float squ   = sqrtf(2.0f * sppf);          // u = squ*e  -> u_n*u_c = 2*spp*en*e
    const float LOG2E = 1.4426950408889634f;

    // guidance pre-scale: cg = sqrt(sig*log2e)*g  -> dist accumulates in exp2 units
    float sq[9];
#pragma unroll
    for (int g = 0; g < 9; ++g) sq[g] = sqrtf(sigma_inv[g] * LOG2E);

    const int cbase = (y * WW + x) * TTT + t0;

    // ---- center data (4 centers) ----
    float cg[9][4];
#pragma unroll
    for (int g = 0; g < 9; ++g) {
        F4 a; a.v = *(const float4*)(guidance + (size_t)g * PLANE + cbase);
#pragma unroll
        for (int s = 0; s < 4; ++s) cg[g][s] = sq[g] * a.f[s];
    }
    // pad-neighbor distance (guidance pad = 0): hc = sum cg^2  (already in exp2 units)
    float hc[4] = {0.f, 0.f, 0.f, 0.f};
#pragma unroll
    for (int s = 0; s < 4; ++s)
#pragma unroll
        for (int g = 0; g < 9; ++g) hc[s] = fmaf(cg[g][s], cg[g][s], hc[s]);

    float cu[3][4], cq[3][4], mq[4];
    {
        F4 e[3], vv[3];
#pragma unroll
        for (int c = 0; c < 3; ++c) {
            e[c].v  = *(const float4*)(estimands + (size_t)c * PLANE + cbase);
            vv[c].v = *(const float4*)(variance  + (size_t)c * PLANE + cbase);
        }
#pragma unroll
        for (int s = 0; s < 4; ++s) {
            float mp = -1e30f;
#pragma unroll
            for (int c = 0; c < 3; ++c) {
                const float ec = e[c].f[s], vc = vv[c].f[s];
                cu[c][s] = squ * ec;
                cq[c][s] = fmaf(sppf * ec, ec, -T2f * vc);
                // pad z-stat: en=-2, vn=0 -> spp*(e+2)^2 - T2*v
                const float ep = ec + 2.0f;
                mp = fmaxf(mp, fmaf(sppf * ep, ep, -T2f * vc));
            }
            mq[s] = mp;
        }
    }

    float num0[4] = {}, num1[4] = {}, num2[4] = {}, den[4] = {};

    for (int dy = -3; dy <= 3; ++dy) {
        const int yy  = y + dy;
        const int ycl = min(max(yy, 0), HH - 1);
        const bool yok = (yy == ycl);
        for (int dx = -3; dx <= 3; ++dx) {
            const int xx  = x + dx;
            const int xcl = min(max(xx, 0), WW - 1);
            const bool xyok = yok && (xx == xcl);
            const int nb = (ycl * WW + xcl) * TTT;
#pragma unroll
            for (int k = 0; k < 3; ++k) {
                const int tcl = t0 - 4 + 4 * k;                 // logical chunk start
                const int tcc = min(max(tcl, 0), TTT - 4);      // clamped (in-bounds) load addr
                F4 wg[9], we[3], wv[3], wi[3];
#pragma unroll
                for (int g = 0; g < 9; ++g)
                    wg[g].v = *(const float4*)(guidance + (size_t)g * PLANE + nb + tcc);
#pragma unroll
                for (int c = 0; c < 3; ++c) {
                    we[c].v = *(const float4*)(estimands + (size_t)c * PLANE + nb + tcc);
                    wv[c].v = *(const float4*)(variance  + (size_t)c * PLANE + nb + tcc);
                    wi[c].v = *(const float4*)(images    + (size_t)c * PLANE + nb + tcc);
                }
#pragma unroll
                for (int s = 0; s < 4; ++s) {
                    const int rel = -4 + 4 * k + s;             // neighbor t rel. to t0 (compile-time)
                    if (rel < -2 || rel > 5) continue;          // pairs only for rel in [-2,5]
                    const int tn = t0 + rel;
                    const bool valid = xyok && ((unsigned)tn < (unsigned)TTT);

                    float ng[9];
#pragma unroll
                    for (int g = 0; g < 9; ++g) ng[g] = sq[g] * wg[g].f[s];
                    float nu[3], nq[3];
#pragma unroll
                    for (int c = 0; c < 3; ++c) {
                        const float ec = we[c].f[s], vc = wv[c].f[s];
                        nu[c] = squ * ec;
                        nq[c] = fmaf(sppf * ec, ec, -T2f * vc);
                    }
#pragma unroll
                    for (int dt = -2; dt <= 2; ++dt) {
                        const int r = rel - dt;                 // center slot (compile-time)
                        if (r < 0 || r > 3) continue;
                        float dist = 0.f;
#pragma unroll
                        for (int g = 0; g < 9; ++g) {
                            const float d = ng[g] - cg[g][r];
                            dist = fmaf(d, d, dist);
                        }
                        const float dsel = valid ? dist : hc[r];    // pad distance if OOB
                        const float w = EXP2F(-dsel);
                        float m0 = fmaf(-nu[0], cu[0][r], nq[0] + cq[0][r]);
                        float m1 = fmaf(-nu[1], cu[1][r], nq[1] + cq[1][r]);
                        float m2 = fmaf(-nu[2], cu[2][r], nq[2] + cq[2][r]);
                        float m  = fmaxf(m0, fmaxf(m1, m2));
                        m = valid ? m : mq[r];                      // pad z-stat if OOB
                        const float wgt  = (m <= 0.f) ? w : 0.f;
                        const float wnum = valid ? wgt : 0.f;       // pad image = 0
                        num0[r] = fmaf(wnum, wi[0].f[s], num0[r]);
                        num1[r] = fmaf(wnum, wi[1].f[s], num1[r]);
                        num2[r] = fmaf(wnum, wi[2].f[s], num2[r]);
                        den[r] += wgt;
                    }
                }
            }
        }
    }

#pragma unroll
    for (int s = 0; s < 4; ++s) den[s] = 1.0f / den[s];
    F4 o0, o1, o2;
#pragma unroll
    for (int s = 0; s < 4; ++s) {
        o0.f[s] = num0[s] * den[s];
        o1.f[s] = num1[s] * den[s];
        o2.f[s] = num2[s] * den[s];
    }
    *(float4*)(out + 0 * (size_t)PLANE + cbase) = o0.v;
    *(float4*)(out + 1 * (size_t)PLANE + cbase) = o1.v;
    *(float4*)(out + 2 * (size_t)PLANE + cbase) = o2.v;
}

extern "C" void kernel_launch(void* const* d_in, const int* in_sizes, int n_in,
                              void* d_out, int out_size, void* d_ws, size_t ws_size,
                              hipStream_t stream)
{
    (void)in_sizes; (void)n_in; (void)out_size; (void)d_ws; (void)ws_size;
    const float* images    = (const float*)d_in[0];
    const float* guidance  = (const float*)d_in[1];
    const float* estimands = (const float*)d_in[2];
    const float* variance  = (const float*)d_in[3];
    const float* sigma_inv = (const float*)d_in[4];
    const int*   spp       = (const int*)d_in[5];

    dim3 grid(WW / 16, HH, 1);
    dim3 block(192, 1, 1);
    hipLaunchKernelGGL(stat_denoise, grid, block, 0, stream,
                       images, guidance, estimands, variance, sigma_inv, spp,
                       (float*)d_out);
}